// Round 1
// baseline (413.122 us; speedup 1.0000x reference)
//
#include <hip/hip_runtime.h>
#include <math.h>

// Problem constants (16 x 1 x 1024 x 1024 fp32 pred/mask -> scalar fp32 loss)
#define BATCH 16
#define H 1024
#define W 1024
#define TILE 64
#define HALO 15                 // max pad = 31/2
#define HREG (TILE + 2 * HALO)  // 94: halo region side
#define SROWS (HREG + 1)        // 95: SAT rows (row 0 = zeros)
#define SCOLS 96                // SAT row stride (col 0 = zeros, col 95 = pad)

// d_ws accumulator layout: acc[b*4 + {0:weit,1:weit*bce,2:inter,3:union}], acc[64] = sum|sig-m|
#define ACC_N 65

__global__ __launch_bounds__(256)
void adaptive_loss_main(const float* __restrict__ pred,
                        const float* __restrict__ mask,
                        float* __restrict__ acc) {
    __shared__ float sat[SROWS * SCOLS];
    __shared__ float red[4][5];

    const int tid = threadIdx.x;
    const int b   = blockIdx.z;
    const int ty0 = blockIdx.y * TILE;
    const int tx0 = blockIdx.x * TILE;
    const float* mimg = mask + (size_t)b * H * W;
    const float* pimg = pred + (size_t)b * H * W;

    // ---- Phase 0: load zero-padded halo into sat[1..94][1..94]; zero borders ----
    for (int idx = tid; idx < SROWS * SCOLS; idx += 256) {
        int r = idx / SCOLS;
        int c = idx - r * SCOLS;
        float v = 0.0f;
        if (r >= 1 && c >= 1 && c <= HREG) {
            int gy = ty0 - HALO + (r - 1);
            int gx = tx0 - HALO + (c - 1);
            if (gy >= 0 && gy < H && gx >= 0 && gx < W)
                v = mimg[gy * W + gx];
        }
        sat[idx] = v;
    }
    __syncthreads();

    // ---- Phase 1: row prefix (thread per row, rows 1..94, cols 1..94) ----
    if (tid < HREG) {
        float carry = 0.0f;
        int base = (tid + 1) * SCOLS;
        for (int c = 1; c <= HREG; ++c) {
            carry += sat[base + c];
            sat[base + c] = carry;
        }
    }
    __syncthreads();

    // ---- Phase 2: col prefix (thread per col, cols 1..94, rows 1..94) ----
    if (tid < HREG) {
        float carry = 0.0f;
        const int c = tid + 1;
        for (int r = 1; r <= HREG; ++r) {
            carry += sat[r * SCOLS + c];
            sat[r * SCOLS + c] = carry;
        }
    }
    __syncthreads();

    // ---- Phase 3: per-pixel fused compute + thread-local partial sums ----
    float s_w = 0.0f, s_wb = 0.0f, s_in = 0.0f, s_un = 0.0f, s_mae = 0.0f;

    const int pp[3]  = {1, 7, 15};
    const float inv[3] = {1.0f / 9.0f, 1.0f / 225.0f, 1.0f / 961.0f};

    #pragma unroll
    for (int i = 0; i < (TILE * TILE) / 256; ++i) {
        int p = tid + 256 * i;
        int y = p >> 6;
        int x = p & 63;
        int gy = ty0 + y, gx = tx0 + x;
        float m  = mimg[gy * W + gx];
        float pr = pimg[gy * W + gx];

        // SAT coordinates: pixel (y,x) of tile <-> halo (y+15, x+15)
        int rc = y + HALO + 1;  // y+16
        int cc = x + HALO + 1;  // x+16
        float w = 0.0f;
        #pragma unroll
        for (int j = 0; j < 3; ++j) {
            int r2 = rc + pp[j], r1 = rc - pp[j] - 1;
            int c2 = cc + pp[j], c1 = cc - pp[j] - 1;
            float s = sat[r2 * SCOLS + c2] - sat[r1 * SCOLS + c2]
                    - sat[r2 * SCOLS + c1] + sat[r1 * SCOLS + c1];
            w += fabsf(s * inv[j] - m);
        }
        float weit = 1.0f + 5.0f * w;
        float bce  = fmaxf(pr, 0.0f) - pr * m + log1pf(expf(-fabsf(pr)));
        float sig  = 1.0f / (1.0f + expf(-pr));

        s_w   += weit;
        s_wb  += weit * bce;
        s_in  += sig * m * weit;
        s_un  += (sig + m) * weit;
        s_mae += fabsf(sig - m);
    }

    // ---- Phase 4: block reduction (wave shuffle, then LDS across 4 waves) ----
    #pragma unroll
    for (int off = 32; off > 0; off >>= 1) {
        s_w   += __shfl_down(s_w,   off);
        s_wb  += __shfl_down(s_wb,  off);
        s_in  += __shfl_down(s_in,  off);
        s_un  += __shfl_down(s_un,  off);
        s_mae += __shfl_down(s_mae, off);
    }
    int wave = tid >> 6, lane = tid & 63;
    if (lane == 0) {
        red[wave][0] = s_w;  red[wave][1] = s_wb; red[wave][2] = s_in;
        red[wave][3] = s_un; red[wave][4] = s_mae;
    }
    __syncthreads();
    if (tid == 0) {
        float r0 = 0, r1 = 0, r2 = 0, r3 = 0, r4 = 0;
        #pragma unroll
        for (int wv = 0; wv < 4; ++wv) {
            r0 += red[wv][0]; r1 += red[wv][1]; r2 += red[wv][2];
            r3 += red[wv][3]; r4 += red[wv][4];
        }
        atomicAdd(&acc[b * 4 + 0], r0);
        atomicAdd(&acc[b * 4 + 1], r1);
        atomicAdd(&acc[b * 4 + 2], r2);
        atomicAdd(&acc[b * 4 + 3], r3);
        atomicAdd(&acc[64], r4);
    }
}

__global__ void adaptive_loss_finalize(const float* __restrict__ acc,
                                       float* __restrict__ out) {
    if (threadIdx.x == 0 && blockIdx.x == 0) {
        float mae = acc[64] / (float)((size_t)BATCH * H * W);
        float tot = 0.0f;
        for (int b = 0; b < BATCH; ++b) {
            float Sw  = acc[b * 4 + 0];
            float Swb = acc[b * 4 + 1];
            float Si  = acc[b * 4 + 2];
            float Su  = acc[b * 4 + 3];
            float wbce = Swb / Sw;
            float wiou = 1.0f - (Si + 1.0f) / (Su - Si + 1.0f);
            float wmae = mae * Sw / (Sw - (float)(H * W));
            tot += 0.7f * (wbce + wiou + wmae);
        }
        out[0] = tot / (float)BATCH;
    }
}

extern "C" void kernel_launch(void* const* d_in, const int* in_sizes, int n_in,
                              void* d_out, int out_size, void* d_ws, size_t ws_size,
                              hipStream_t stream) {
    const float* pred = (const float*)d_in[0];
    const float* mask = (const float*)d_in[1];
    float* acc = (float*)d_ws;

    hipMemsetAsync(acc, 0, ACC_N * sizeof(float), stream);

    dim3 grid(W / TILE, H / TILE, BATCH);
    adaptive_loss_main<<<grid, 256, 0, stream>>>(pred, mask, acc);
    adaptive_loss_finalize<<<1, 64, 0, stream>>>(acc, (float*)d_out);
}

// Round 2
// 310.955 us; speedup vs baseline: 1.3286x; 1.3286x over previous
//
#include <hip/hip_runtime.h>
#include <math.h>

// Problem constants (16 x 1 x 1024 x 1024 fp32 pred/mask -> scalar fp32 loss)
#define BATCH 16
#define H 1024
#define W 1024
#define TILE 64
#define HALO 15                 // max pad = 31/2
#define HREG (TILE + 2 * HALO)  // 94: halo region side
#define SROWS (HREG + 1)        // 95: SAT rows (row 0 = zeros)
#define SCOLS 97                // SAT row stride: 97 % 32 == 1 -> row-walk scans hit all banks
                                // (96 put every lane of phase-1 on bank 0: 7e7 conflict cycles)

// d_ws accumulator layout: acc[b*5 + {0:weit,1:weit*bce,2:inter,3:union,4:mae}]
#define ACC_N (BATCH * 5)

__global__ __launch_bounds__(256)
void adaptive_loss_main(const float* __restrict__ pred,
                        const float* __restrict__ mask,
                        float* __restrict__ acc) {
    __shared__ float sat[SROWS * SCOLS];
    __shared__ float red[4][5];

    const int tid = threadIdx.x;
    const int b   = blockIdx.z;
    const int ty0 = blockIdx.y * TILE;
    const int tx0 = blockIdx.x * TILE;
    const float* mimg = mask + (size_t)b * H * W;
    const float* pimg = pred + (size_t)b * H * W;

    // ---- Phase 0: load zero-padded halo into sat[1..94][1..94]; zero borders ----
    for (int idx = tid; idx < SROWS * SCOLS; idx += 256) {
        int r = idx / SCOLS;
        int c = idx - r * SCOLS;
        float v = 0.0f;
        if (r >= 1 && c >= 1 && c <= HREG) {
            int gy = ty0 - HALO + (r - 1);
            int gx = tx0 - HALO + (c - 1);
            if (gy >= 0 && gy < H && gx >= 0 && gx < W)
                v = mimg[gy * W + gx];
        }
        sat[idx] = v;
    }
    __syncthreads();

    // ---- Phase 1: row prefix (thread per row; stride-97 rows -> conflict-free) ----
    if (tid < HREG) {
        float carry = 0.0f;
        int base = (tid + 1) * SCOLS;
        for (int c = 1; c <= HREG; ++c) {
            carry += sat[base + c];
            sat[base + c] = carry;
        }
    }
    __syncthreads();

    // ---- Phase 2: col prefix (thread per col; consecutive-lane cols -> conflict-free) ----
    if (tid < HREG) {
        float carry = 0.0f;
        const int c = tid + 1;
        for (int r = 1; r <= HREG; ++r) {
            carry += sat[r * SCOLS + c];
            sat[r * SCOLS + c] = carry;
        }
    }
    __syncthreads();

    // ---- Phase 3: per-pixel fused compute, float4 global loads ----
    float s_w = 0.0f, s_wb = 0.0f, s_in = 0.0f, s_un = 0.0f, s_mae = 0.0f;

    const int pp[3]    = {1, 7, 15};
    const float inv[3] = {1.0f / 9.0f, 1.0f / 225.0f, 1.0f / 961.0f};

    #pragma unroll
    for (int i = 0; i < 4; ++i) {
        int y  = (tid >> 4) + 16 * i;   // 0..63
        int x4 = (tid & 15) << 2;       // 0,4,...,60
        int gy = ty0 + y, gx = tx0 + x4;
        const float4 m4 = *(const float4*)(mimg + (size_t)gy * W + gx);
        const float4 p4 = *(const float4*)(pimg + (size_t)gy * W + gx);
        const int rc = y + HALO + 1;

        #pragma unroll
        for (int q = 0; q < 4; ++q) {
            float m  = (&m4.x)[q];
            float pr = (&p4.x)[q];
            int cc = x4 + q + HALO + 1;

            float w = 0.0f;
            #pragma unroll
            for (int j = 0; j < 3; ++j) {
                int r2 = (rc + pp[j]) * SCOLS, r1 = (rc - pp[j] - 1) * SCOLS;
                int c2 = cc + pp[j],           c1 = cc - pp[j] - 1;
                float s = sat[r2 + c2] - sat[r1 + c2]
                        - sat[r2 + c1] + sat[r1 + c1];
                w += fabsf(s * inv[j] - m);
            }
            float weit = 1.0f + 5.0f * w;
            float t    = __expf(-fabsf(pr));                 // shared by bce & sigmoid
            float bce  = fmaxf(pr, 0.0f) - pr * m + __logf(1.0f + t);
            float u    = __builtin_amdgcn_rcpf(1.0f + t);    // 1/(1+e^-|pr|)
            float sig  = (pr >= 0.0f) ? u : 1.0f - u;

            s_w   += weit;
            s_wb  += weit * bce;
            s_in  += sig * m * weit;
            s_un  += (sig + m) * weit;
            s_mae += fabsf(sig - m);
        }
    }

    // ---- Phase 4: block reduction (wave shuffle, then LDS across 4 waves) ----
    #pragma unroll
    for (int off = 32; off > 0; off >>= 1) {
        s_w   += __shfl_down(s_w,   off);
        s_wb  += __shfl_down(s_wb,  off);
        s_in  += __shfl_down(s_in,  off);
        s_un  += __shfl_down(s_un,  off);
        s_mae += __shfl_down(s_mae, off);
    }
    int wave = tid >> 6, lane = tid & 63;
    if (lane == 0) {
        red[wave][0] = s_w;  red[wave][1] = s_wb; red[wave][2] = s_in;
        red[wave][3] = s_un; red[wave][4] = s_mae;
    }
    __syncthreads();
    if (tid == 0) {
        float r0 = 0, r1 = 0, r2 = 0, r3 = 0, r4 = 0;
        #pragma unroll
        for (int wv = 0; wv < 4; ++wv) {
            r0 += red[wv][0]; r1 += red[wv][1]; r2 += red[wv][2];
            r3 += red[wv][3]; r4 += red[wv][4];
        }
        atomicAdd(&acc[b * 5 + 0], r0);
        atomicAdd(&acc[b * 5 + 1], r1);
        atomicAdd(&acc[b * 5 + 2], r2);
        atomicAdd(&acc[b * 5 + 3], r3);
        atomicAdd(&acc[b * 5 + 4], r4);
    }
}

__global__ void adaptive_loss_finalize(const float* __restrict__ acc,
                                       float* __restrict__ out) {
    if (threadIdx.x == 0 && blockIdx.x == 0) {
        float smae = 0.0f;
        for (int b = 0; b < BATCH; ++b) smae += acc[b * 5 + 4];
        float mae = smae / (float)((size_t)BATCH * H * W);
        float tot = 0.0f;
        for (int b = 0; b < BATCH; ++b) {
            float Sw  = acc[b * 5 + 0];
            float Swb = acc[b * 5 + 1];
            float Si  = acc[b * 5 + 2];
            float Su  = acc[b * 5 + 3];
            float wbce = Swb / Sw;
            float wiou = 1.0f - (Si + 1.0f) / (Su - Si + 1.0f);
            float wmae = mae * Sw / (Sw - (float)(H * W));
            tot += 0.7f * (wbce + wiou + wmae);
        }
        out[0] = tot / (float)BATCH;
    }
}

extern "C" void kernel_launch(void* const* d_in, const int* in_sizes, int n_in,
                              void* d_out, int out_size, void* d_ws, size_t ws_size,
                              hipStream_t stream) {
    const float* pred = (const float*)d_in[0];
    const float* mask = (const float*)d_in[1];
    float* acc = (float*)d_ws;

    hipMemsetAsync(acc, 0, ACC_N * sizeof(float), stream);

    dim3 grid(W / TILE, H / TILE, BATCH);
    adaptive_loss_main<<<grid, 256, 0, stream>>>(pred, mask, acc);
    adaptive_loss_finalize<<<1, 64, 0, stream>>>(acc, (float*)d_out);
}